// Round 1
// baseline (2499.609 us; speedup 1.0000x reference)
//
#include <hip/hip_runtime.h>

#define NNODES 4096
#define LWALK 16
#define ODIM 8

// ---------- edge-index dtype detection (int32 vs int64 on device) ----------
__global__ void detect_fmt_k(const void* ei, int E, int* flag) {
    if (blockIdx.x == 0 && threadIdx.x == 0) {
        const long long* p = (const long long*)ei;
        int ok = 1;
        for (int i = 0; i < 64; ++i) {
            long long v = p[i];
            if (v < 0 || v >= NNODES) { ok = 0; break; }
        }
        *flag = ok;  // 1 => int64 layout, 0 => int32 layout
    }
}

__device__ __forceinline__ int load_idx(const void* p, int i, int fmt) {
    if (fmt) return (int)((const long long*)p)[i];
    return ((const int*)p)[i];
}

// ---------- degree + in-degree counts ----------
__global__ void build_deg_cnt_k(const void* ei, int E, int* deg, int* cnt,
                                const int* fmt) {
    int e = blockIdx.x * blockDim.x + threadIdx.x;
    if (e >= E) return;
    int f = *fmt;
    int r = load_idx(ei, e, f);
    int c = load_idx(ei, E + e, f);
    atomicAdd(&deg[r], 1);
    atomicAdd(&cnt[c], 1);
}

// ---------- exclusive scan over 4096 counts (single block, 1024 threads) ----------
__global__ void scan_k(const int* __restrict__ cnt, int* __restrict__ rowptr,
                       int* __restrict__ cursor) {
    __shared__ int sm[1024];
    int tid = threadIdx.x;
    int v0 = cnt[4 * tid + 0], v1 = cnt[4 * tid + 1];
    int v2 = cnt[4 * tid + 2], v3 = cnt[4 * tid + 3];
    int tsum = v0 + v1 + v2 + v3;
    sm[tid] = tsum;
    __syncthreads();
    int val = tsum;
    for (int off = 1; off < 1024; off <<= 1) {
        int t = (tid >= off) ? sm[tid - off] : 0;
        __syncthreads();
        val += t;
        sm[tid] = val;
        __syncthreads();
    }
    int excl = val - tsum;  // exclusive prefix of thread sums
    int p0 = excl, p1 = excl + v0, p2 = p1 + v1, p3 = p2 + v2;
    rowptr[4 * tid + 0] = p0; rowptr[4 * tid + 1] = p1;
    rowptr[4 * tid + 2] = p2; rowptr[4 * tid + 3] = p3;
    cursor[4 * tid + 0] = p0; cursor[4 * tid + 1] = p1;
    cursor[4 * tid + 2] = p2; cursor[4 * tid + 3] = p3;
    if (tid == 1023) rowptr[4096] = val;
}

// ---------- counting-sort fill of column-CSR ----------
__global__ void fill_csr_k(const void* ei, int E, const int* __restrict__ deg,
                           int* cursor, int* __restrict__ srcs,
                           float* __restrict__ vals, const int* fmt) {
    int e = blockIdx.x * blockDim.x + threadIdx.x;
    if (e >= E) return;
    int f = *fmt;
    int r = load_idx(ei, e, f);
    int c = load_idx(ei, E + e, f);
    int pos = atomicAdd(&cursor[c], 1);
    int d = deg[r];
    srcs[pos] = r;
    vals[pos] = 1.0f / (float)(d < 1 ? 1 : d);
}

// ---------- buffer init ----------
__global__ void zero4_k(float4* p, long long n4) {
    long long i = (long long)blockIdx.x * blockDim.x + threadIdx.x;
    if (i < n4) p[i] = make_float4(0.f, 0.f, 0.f, 0.f);
}

__global__ void ones_k(float* X, int base, int S) {
    int j = blockIdx.x * blockDim.x + threadIdx.x;
    if (j < S) X[(long long)(base + j) * S + j] = 1.0f;
}

// ---------- main SpMM step: Y[c,:] = sum_{in-edges (r->c)} val * X[r,:] ----------
template <int S>
__global__ __launch_bounds__(S / 4) void spmm_k(
    const float* __restrict__ X, float* __restrict__ Y,
    const int* __restrict__ rowptr, const int* __restrict__ srcs,
    const float* __restrict__ vals) {
    const int c = blockIdx.x;
    const int tid = threadIdx.x;  // S/4 threads, one float4 each
    int beg = rowptr[c], end = rowptr[c + 1];
    float4 acc = make_float4(0.f, 0.f, 0.f, 0.f);
    const float4* Xv = (const float4*)X;
    for (int e = beg; e < end; ++e) {
        int r = srcs[e];
        float v = vals[e];
        float4 x = Xv[(long long)r * (S / 4) + tid];
        acc.x = fmaf(v, x.x, acc.x);
        acc.y = fmaf(v, x.y, acc.y);
        acc.z = fmaf(v, x.z, acc.z);
        acc.w = fmaf(v, x.w, acc.w);
    }
    ((float4*)Y)[(long long)c * (S / 4) + tid] = acc;
}

// ---------- diagonal extraction ----------
__global__ void diag_k(const float* __restrict__ Y, float* __restrict__ rw,
                       int base, int S, int k) {
    int j = blockIdx.x * blockDim.x + threadIdx.x;
    if (j < S)
        rw[(long long)(base + j) * LWALK + k] = Y[(long long)(base + j) * S + j];
}

// ---------- final linear: out[s,d] = b[d] + sum_k rw[s,k]*W[d,k] ----------
__global__ void linear_k(const float* __restrict__ rw, const float* __restrict__ W,
                         const float* __restrict__ b, float* __restrict__ out) {
    int i = blockIdx.x * blockDim.x + threadIdx.x;
    if (i >= NNODES * ODIM) return;
    int s = i >> 3, d = i & 7;
    float acc = b[d];
#pragma unroll
    for (int k = 0; k < LWALK; ++k)
        acc = fmaf(rw[s * LWALK + k], W[d * LWALK + k], acc);
    out[i] = acc;
}

extern "C" void kernel_launch(void* const* d_in, const int* in_sizes, int n_in,
                              void* d_out, int out_size, void* d_ws, size_t ws_size,
                              hipStream_t stream) {
    const void* ei = d_in[0];
    int E = in_sizes[0] / 2;
    const float* W = (const float*)d_in[2];
    const float* bias = (const float*)d_in[3];
    float* out = (float*)d_out;

    // workspace carve
    char* ws = (char*)d_ws;
    size_t off = 0;
    auto alloc = [&](size_t bytes) -> char* {
        char* p = ws + off;
        off = (off + bytes + 255) & ~(size_t)255;
        return p;
    };
    int* flag = (int*)alloc(4);
    int* deg = (int*)alloc(NNODES * 4);
    int* cnt = (int*)alloc(NNODES * 4);
    int* rowptr = (int*)alloc((NNODES + 1) * 4);
    int* cursor = (int*)alloc(NNODES * 4);
    int* srcs = (int*)alloc((size_t)E * 4);
    float* vals = (float*)alloc((size_t)E * 4);
    float* rw = (float*)alloc(NNODES * LWALK * 4);
    size_t fixed = off;

    // pick largest column-block width S whose ping-pong buffers fit in ws
    const int s_choices[5] = {4096, 2048, 1024, 512, 256};
    int S = 256;
    for (int i = 0; i < 5; ++i) {
        if (fixed + 2ull * NNODES * s_choices[i] * 4 <= ws_size) {
            S = s_choices[i];
            break;
        }
    }
    float* Xb = (float*)alloc((size_t)NNODES * S * 4);
    float* Yb = (float*)alloc((size_t)NNODES * S * 4);

    hipMemsetAsync(deg, 0, NNODES * 4, stream);
    hipMemsetAsync(cnt, 0, NNODES * 4, stream);
    detect_fmt_k<<<1, 64, 0, stream>>>(ei, E, flag);
    build_deg_cnt_k<<<(E + 255) / 256, 256, 0, stream>>>(ei, E, deg, cnt, flag);
    scan_k<<<1, 1024, 0, stream>>>(cnt, rowptr, cursor);
    fill_csr_k<<<(E + 255) / 256, 256, 0, stream>>>(ei, E, deg, cursor, srcs, vals, flag);

    long long n4 = (long long)NNODES * S / 4;
    int zblocks = (int)((n4 + 255) / 256);

    for (int base = 0; base < NNODES; base += S) {
        zero4_k<<<zblocks, 256, 0, stream>>>((float4*)Xb, n4);
        ones_k<<<(S + 255) / 256, 256, 0, stream>>>(Xb, base, S);
        float* X = Xb;
        float* Y = Yb;
        for (int k = 0; k < LWALK; ++k) {
            switch (S) {
                case 4096: spmm_k<4096><<<NNODES, 1024, 0, stream>>>(X, Y, rowptr, srcs, vals); break;
                case 2048: spmm_k<2048><<<NNODES, 512, 0, stream>>>(X, Y, rowptr, srcs, vals); break;
                case 1024: spmm_k<1024><<<NNODES, 256, 0, stream>>>(X, Y, rowptr, srcs, vals); break;
                case 512:  spmm_k<512><<<NNODES, 128, 0, stream>>>(X, Y, rowptr, srcs, vals); break;
                default:   spmm_k<256><<<NNODES, 64, 0, stream>>>(X, Y, rowptr, srcs, vals); break;
            }
            diag_k<<<(S + 255) / 256, 256, 0, stream>>>(Y, rw, base, S, k);
            float* t = X; X = Y; Y = t;
        }
    }
    linear_k<<<(NNODES * ODIM + 255) / 256, 256, 0, stream>>>(rw, W, bias, out);
}

// Round 2
// 788.653 us; speedup vs baseline: 3.1695x; 3.1695x over previous
//
#include <hip/hip_runtime.h>
#include <hip/hip_fp16.h>

#define NNODES 4096
#define LWALK 16
#define ODIM 8

// ---------- edge-index dtype detection (int32 vs int64 on device) ----------
__global__ void detect_fmt_k(const void* ei, int E, int* flag) {
    if (blockIdx.x == 0 && threadIdx.x == 0) {
        const long long* p = (const long long*)ei;
        int ok = 1;
        for (int i = 0; i < 64; ++i) {
            long long v = p[i];
            if (v < 0 || v >= NNODES) { ok = 0; break; }
        }
        *flag = ok;  // 1 => int64 layout, 0 => int32 layout
    }
}

__device__ __forceinline__ int load_idx(const void* p, int i, int fmt) {
    if (fmt) return (int)((const long long*)p)[i];
    return ((const int*)p)[i];
}

// ---------- degree + in-degree counts ----------
__global__ void build_deg_cnt_k(const void* ei, int E, int* deg, int* cnt,
                                const int* fmt) {
    int e = blockIdx.x * blockDim.x + threadIdx.x;
    if (e >= E) return;
    int f = *fmt;
    int r = load_idx(ei, e, f);
    int c = load_idx(ei, E + e, f);
    atomicAdd(&deg[r], 1);
    atomicAdd(&cnt[c], 1);
}

// ---------- exclusive scan over 4096 counts (single block, 1024 threads) ----------
__global__ void scan_k(const int* __restrict__ cnt, int* __restrict__ rowptr,
                       int* __restrict__ cursor) {
    __shared__ int sm[1024];
    int tid = threadIdx.x;
    int v0 = cnt[4 * tid + 0], v1 = cnt[4 * tid + 1];
    int v2 = cnt[4 * tid + 2], v3 = cnt[4 * tid + 3];
    int tsum = v0 + v1 + v2 + v3;
    sm[tid] = tsum;
    __syncthreads();
    int val = tsum;
    for (int off = 1; off < 1024; off <<= 1) {
        int t = (tid >= off) ? sm[tid - off] : 0;
        __syncthreads();
        val += t;
        sm[tid] = val;
        __syncthreads();
    }
    int excl = val - tsum;
    int p0 = excl, p1 = excl + v0, p2 = p1 + v1, p3 = p2 + v2;
    rowptr[4 * tid + 0] = p0; rowptr[4 * tid + 1] = p1;
    rowptr[4 * tid + 2] = p2; rowptr[4 * tid + 3] = p3;
    cursor[4 * tid + 0] = p0; cursor[4 * tid + 1] = p1;
    cursor[4 * tid + 2] = p2; cursor[4 * tid + 3] = p3;
    if (tid == 1023) rowptr[4096] = val;
}

// ---------- counting-sort fill of column-CSR ----------
__global__ void fill_csr_k(const void* ei, int E, const int* __restrict__ deg,
                           int* cursor, int* __restrict__ srcs,
                           float* __restrict__ vals, const int* fmt) {
    int e = blockIdx.x * blockDim.x + threadIdx.x;
    if (e >= E) return;
    int f = *fmt;
    int r = load_idx(ei, e, f);
    int c = load_idx(ei, E + e, f);
    int pos = atomicAdd(&cursor[c], 1);
    int d = deg[r];
    srcs[pos] = r;
    vals[pos] = 1.0f / (float)(d < 1 ? 1 : d);
}

// ---------- init X0 = I (fp16) ----------
__global__ void zeroh_k(uint4* p, long long n) {
    long long i = (long long)blockIdx.x * blockDim.x + threadIdx.x;
    if (i < n) p[i] = make_uint4(0u, 0u, 0u, 0u);
}

__global__ void eyeh_k(__half* X) {
    int i = blockIdx.x * blockDim.x + threadIdx.x;
    if (i < NNODES) X[(size_t)i * NNODES + i] = __float2half(1.0f);
}

// ---------- SpMM step (fp16 storage, fp32 accumulate) ----------
// Y[c,:] = sum_{in-edges (r->c)} val * X[r,:]
__global__ __launch_bounds__(512) void spmm_h_k(
    const __half* __restrict__ X, __half* __restrict__ Y,
    const int* __restrict__ rowptr, const int* __restrict__ srcs,
    const float* __restrict__ vals) {
    const int c = blockIdx.x;
    const int tid = threadIdx.x;  // 512 threads x 8 halves = 4096
    int beg = rowptr[c], end = rowptr[c + 1];
    float acc[8];
#pragma unroll
    for (int u = 0; u < 8; ++u) acc[u] = 0.f;
    for (int e = beg; e < end; ++e) {
        int r = srcs[e];
        float v = vals[e];
        uint4 x = ((const uint4*)(X + (size_t)r * NNODES))[tid];
        const __half2* xh = (const __half2*)&x;
#pragma unroll
        for (int u = 0; u < 4; ++u) {
            float2 f = __half22float2(xh[u]);
            acc[2 * u]     = fmaf(v, f.x, acc[2 * u]);
            acc[2 * u + 1] = fmaf(v, f.y, acc[2 * u + 1]);
        }
    }
    uint4 o;
    __half2* oh = (__half2*)&o;
#pragma unroll
    for (int u = 0; u < 4; ++u) oh[u] = __floats2half2_rn(acc[2 * u], acc[2 * u + 1]);
    ((uint4*)(Y + (size_t)c * NNODES))[tid] = o;
}

// ---------- direct diagonal: rw[i,k] = X_m[i,i] ----------
__global__ void diag_h_k(const __half* __restrict__ Xm, float* __restrict__ rw, int k) {
    int i = blockIdx.x * blockDim.x + threadIdx.x;
    if (i < NNODES) rw[i * LWALK + k] = __half2float(Xm[(size_t)i * NNODES + i]);
}

// ---------- paired diagonal: rw[i,col] += sum_j A[i,j] * B[j,i] ----------
// grid (64, NJ): blockIdx.x = i-tile (64 i's), blockIdx.y = J-chunk.
__global__ __launch_bounds__(256) void pairdiag_k(
    const __half* __restrict__ A, const __half* __restrict__ B,
    float* __restrict__ rw, int col) {
    __shared__ float bt[64][65];
    const int i0 = blockIdx.x * 64;
    const int t = threadIdx.x;
    const int li = t >> 2;        // [0,64)
    const int q = t & 3;          // [0,4)
    const int c0 = q * 16;
    const int Jbeg = blockIdx.y * (NNODES / 8);
    const int Jend = Jbeg + (NNODES / 8);
    float acc = 0.f;
    for (int J = Jbeg; J < Jend; J += 64) {
        // load B tile [J..J+64) x [i0..i0+64), transpose into LDS
        const __half* bp = B + (size_t)(J + li) * NNODES + i0 + c0;
        uint4 b0 = *(const uint4*)bp;
        uint4 b1 = *(const uint4*)(bp + 8);
        __syncthreads();  // protect previous iteration's bt reads
        const __half* bh0 = (const __half*)&b0;
        const __half* bh1 = (const __half*)&b1;
#pragma unroll
        for (int s = 0; s < 8; ++s) bt[c0 + s][li] = __half2float(bh0[s]);
#pragma unroll
        for (int s = 0; s < 8; ++s) bt[c0 + 8 + s][li] = __half2float(bh1[s]);
        __syncthreads();
        // A row segment: A[i0+li, J+q*16 .. +16)
        const __half* ap = A + (size_t)(i0 + li) * NNODES + J + c0;
        uint4 a0 = *(const uint4*)ap;
        uint4 a1 = *(const uint4*)(ap + 8);
        const __half* ah0 = (const __half*)&a0;
        const __half* ah1 = (const __half*)&a1;
#pragma unroll
        for (int s = 0; s < 8; ++s)
            acc = fmaf(__half2float(ah0[s]), bt[li][c0 + s], acc);
#pragma unroll
        for (int s = 0; s < 8; ++s)
            acc = fmaf(__half2float(ah1[s]), bt[li][c0 + 8 + s], acc);
    }
    // reduce the 4 q-partials per i (lanes li*4+q are consecutive)
    acc += __shfl_xor(acc, 1);
    acc += __shfl_xor(acc, 2);
    if (q == 0) atomicAdd(&rw[(i0 + li) * LWALK + col], acc);
}

// ---------- final linear ----------
__global__ void linear_k(const float* __restrict__ rw, const float* __restrict__ W,
                         const float* __restrict__ b, float* __restrict__ out) {
    int i = blockIdx.x * blockDim.x + threadIdx.x;
    if (i >= NNODES * ODIM) return;
    int s = i >> 3, d = i & 7;
    float acc = b[d];
#pragma unroll
    for (int k = 0; k < LWALK; ++k)
        acc = fmaf(rw[s * LWALK + k], W[d * LWALK + k], acc);
    out[i] = acc;
}

extern "C" void kernel_launch(void* const* d_in, const int* in_sizes, int n_in,
                              void* d_out, int out_size, void* d_ws, size_t ws_size,
                              hipStream_t stream) {
    const void* ei = d_in[0];
    int E = in_sizes[0] / 2;
    const float* W = (const float*)d_in[2];
    const float* bias = (const float*)d_in[3];
    float* out = (float*)d_out;

    char* ws = (char*)d_ws;
    size_t off = 0;
    auto alloc = [&](size_t bytes) -> char* {
        char* p = ws + off;
        off = (off + bytes + 255) & ~(size_t)255;
        return p;
    };
    int* flag = (int*)alloc(4);
    int* deg = (int*)alloc(NNODES * 4);
    int* cnt = (int*)alloc(NNODES * 4);
    int* rowptr = (int*)alloc((NNODES + 1) * 4);
    int* cursor = (int*)alloc(NNODES * 4);
    int* srcs = (int*)alloc((size_t)E * 4);
    float* vals = (float*)alloc((size_t)E * 4);
    float* rw = (float*)alloc(NNODES * LWALK * 4);
    __half* Xb = (__half*)alloc((size_t)NNODES * NNODES * 2);
    __half* Yb = (__half*)alloc((size_t)NNODES * NNODES * 2);

    hipMemsetAsync(deg, 0, NNODES * 4, stream);
    hipMemsetAsync(cnt, 0, NNODES * 4, stream);
    hipMemsetAsync(rw, 0, NNODES * LWALK * 4, stream);
    detect_fmt_k<<<1, 64, 0, stream>>>(ei, E, flag);
    build_deg_cnt_k<<<(E + 255) / 256, 256, 0, stream>>>(ei, E, deg, cnt, flag);
    scan_k<<<1, 1024, 0, stream>>>(cnt, rowptr, cursor);
    fill_csr_k<<<(E + 255) / 256, 256, 0, stream>>>(ei, E, deg, cursor, srcs, vals, flag);

    // X0 = I
    long long n16 = (long long)NNODES * NNODES / 8;  // uint4 units
    zeroh_k<<<(int)((n16 + 255) / 256), 256, 0, stream>>>((uint4*)Xb, n16);
    eyeh_k<<<(NNODES + 255) / 256, 256, 0, stream>>>(Xb);

    __half* X = Xb;
    __half* Y = Yb;
    for (int m = 1; m <= 8; ++m) {
        spmm_h_k<<<NNODES, 512, 0, stream>>>(X, Y, rowptr, srcs, vals);
        diag_h_k<<<(NNODES + 255) / 256, 256, 0, stream>>>(Y, rw, m - 1);
        if (m >= 5) {
            dim3 pg(NNODES / 64, 8);
            // odd k = 2m-1: sum_j X_m[i,j] * X_{m-1}[j,i]
            pairdiag_k<<<pg, 256, 0, stream>>>(Y, X, rw, 2 * m - 2);
            // even k = 2m: sum_j X_m[i,j] * X_m[j,i]
            pairdiag_k<<<pg, 256, 0, stream>>>(Y, Y, rw, 2 * m - 1);
        }
        __half* t = X; X = Y; Y = t;
    }
    linear_k<<<(NNODES * ODIM + 255) / 256, 256, 0, stream>>>(rw, W, bias, out);
}

// Round 3
// 623.233 us; speedup vs baseline: 4.0107x; 1.2654x over previous
//
#include <hip/hip_runtime.h>
#include <hip/hip_fp16.h>

#define NNODES 4096
#define LWALK 16
#define ODIM 8

// ---------- edge-index dtype detection (int32 vs int64 on device) ----------
__global__ void detect_fmt_k(const void* ei, int E, int* flag) {
    if (blockIdx.x == 0 && threadIdx.x == 0) {
        const long long* p = (const long long*)ei;
        int ok = 1;
        for (int i = 0; i < 64; ++i) {
            long long v = p[i];
            if (v < 0 || v >= NNODES) { ok = 0; break; }
        }
        *flag = ok;  // 1 => int64 layout, 0 => int32 layout
    }
}

__device__ __forceinline__ int load_idx(const void* p, int i, int fmt) {
    if (fmt) return (int)((const long long*)p)[i];
    return ((const int*)p)[i];
}

// ---------- degree + in-degree counts ----------
__global__ void build_deg_cnt_k(const void* ei, int E, int* deg, int* cnt,
                                const int* fmt) {
    int e = blockIdx.x * blockDim.x + threadIdx.x;
    if (e >= E) return;
    int f = *fmt;
    int r = load_idx(ei, e, f);
    int c = load_idx(ei, E + e, f);
    atomicAdd(&deg[r], 1);
    atomicAdd(&cnt[c], 1);
}

// ---------- exclusive scan over 4096 counts (single block, 1024 threads) ----------
__global__ void scan_k(const int* __restrict__ cnt, int* __restrict__ rowptr,
                       int* __restrict__ cursor) {
    __shared__ int sm[1024];
    int tid = threadIdx.x;
    int v0 = cnt[4 * tid + 0], v1 = cnt[4 * tid + 1];
    int v2 = cnt[4 * tid + 2], v3 = cnt[4 * tid + 3];
    int tsum = v0 + v1 + v2 + v3;
    sm[tid] = tsum;
    __syncthreads();
    int val = tsum;
    for (int off = 1; off < 1024; off <<= 1) {
        int t = (tid >= off) ? sm[tid - off] : 0;
        __syncthreads();
        val += t;
        sm[tid] = val;
        __syncthreads();
    }
    int excl = val - tsum;
    int p0 = excl, p1 = excl + v0, p2 = p1 + v1, p3 = p2 + v2;
    rowptr[4 * tid + 0] = p0; rowptr[4 * tid + 1] = p1;
    rowptr[4 * tid + 2] = p2; rowptr[4 * tid + 3] = p3;
    cursor[4 * tid + 0] = p0; cursor[4 * tid + 1] = p1;
    cursor[4 * tid + 2] = p2; cursor[4 * tid + 3] = p3;
    if (tid == 1023) rowptr[4096] = val;
}

// ---------- counting-sort fill of column-CSR ----------
__global__ void fill_csr_k(const void* ei, int E, const int* __restrict__ deg,
                           int* cursor, int* __restrict__ srcs,
                           float* __restrict__ vals, const int* fmt) {
    int e = blockIdx.x * blockDim.x + threadIdx.x;
    if (e >= E) return;
    int f = *fmt;
    int r = load_idx(ei, e, f);
    int c = load_idx(ei, E + e, f);
    int pos = atomicAdd(&cursor[c], 1);
    int d = deg[r];
    srcs[pos] = r;
    vals[pos] = 1.0f / (float)(d < 1 ? 1 : d);
}

// ---------- init X0 = I (fp16) ----------
__global__ void zeroh_k(uint4* p, long long n) {
    long long i = (long long)blockIdx.x * blockDim.x + threadIdx.x;
    if (i < n) p[i] = make_uint4(0u, 0u, 0u, 0u);
}

__global__ void eyeh_k(__half* X) {
    int i = blockIdx.x * blockDim.x + threadIdx.x;
    if (i < NNODES) X[(size_t)i * NNODES + i] = __float2half(1.0f);
}

// ---------- XCD-pinned slab SpMM (fp16 storage, fp32 accumulate) ----------
// Y[c, slab] = sum_{in-edges (r->c)} val * X[r, slab]
// slab = blockIdx.x & 7 pins each 512-half (1KB/row, 4MB total) column slab
// to one XCD's L2 via the round-robin block->XCD dispatch heuristic.
__global__ __launch_bounds__(128) void spmm_slab_k(
    const __half* __restrict__ X, __half* __restrict__ Y,
    const int* __restrict__ rowptr, const int* __restrict__ srcs,
    const float* __restrict__ vals) {
    const int bid = blockIdx.x;
    const int slab = bid & 7;
    const int c = bid >> 3;
    const int tid = threadIdx.x;            // 128 threads x 4 halves = 512
    const int colo = slab * 512 + tid * 4;  // half offset within a row
    const __half* Xs = X + colo;
    int beg = rowptr[c], end = rowptr[c + 1];
    float a0 = 0.f, a1 = 0.f, a2 = 0.f, a3 = 0.f;
    for (int e = beg; e < end; ++e) {
        int r = srcs[e];
        float v = vals[e];
        uint2 x = *(const uint2*)(Xs + (size_t)r * NNODES);
        __half2 h0 = *(__half2*)&x.x;
        __half2 h1 = *(__half2*)&x.y;
        float2 f0 = __half22float2(h0);
        float2 f1 = __half22float2(h1);
        a0 = fmaf(v, f0.x, a0);
        a1 = fmaf(v, f0.y, a1);
        a2 = fmaf(v, f1.x, a2);
        a3 = fmaf(v, f1.y, a3);
    }
    __half2 o0 = __floats2half2_rn(a0, a1);
    __half2 o1 = __floats2half2_rn(a2, a3);
    unsigned int u0 = *(unsigned int*)&o0;
    unsigned int u1 = *(unsigned int*)&o1;
    unsigned long long up =
        (unsigned long long)u0 | ((unsigned long long)u1 << 32);
    // non-temporal: don't let the streaming Y-write evict the pinned X slab
    __builtin_nontemporal_store(
        up, (unsigned long long*)(Y + (size_t)c * NNODES + colo));
}

// ---------- direct diagonal: rw[i,k] = X_m[i,i] ----------
__global__ void diag_h_k(const __half* __restrict__ Xm, float* __restrict__ rw, int k) {
    int i = blockIdx.x * blockDim.x + threadIdx.x;
    if (i < NNODES) rw[i * LWALK + k] = __half2float(Xm[(size_t)i * NNODES + i]);
}

// ---------- fused paired diagonals (shares the A-row stream):
// rw[i,col_odd]  += sum_j A[i,j] * B[j,i]   (A=X_m, B=X_{m-1})
// rw[i,col_even] += sum_j A[i,j] * A[j,i]
__global__ __launch_bounds__(256) void pairdiag2_k(
    const __half* __restrict__ A, const __half* __restrict__ B,
    float* __restrict__ rw, int col_odd, int col_even) {
    __shared__ float bt[64][65];  // B^T tile
    __shared__ float ct[64][65];  // A^T tile
    const int i0 = blockIdx.x * 64;
    const int t = threadIdx.x;
    const int li = t >> 2;   // [0,64)
    const int q = t & 3;     // [0,4)
    const int c0 = q * 16;
    const int Jbeg = blockIdx.y * (NNODES / 16);
    const int Jend = Jbeg + (NNODES / 16);
    float accO = 0.f, accE = 0.f;
    for (int J = Jbeg; J < Jend; J += 64) {
        const __half* bp = B + (size_t)(J + li) * NNODES + i0 + c0;
        uint4 b0 = *(const uint4*)bp;
        uint4 b1 = *(const uint4*)(bp + 8);
        const __half* cp = A + (size_t)(J + li) * NNODES + i0 + c0;
        uint4 g0 = *(const uint4*)cp;
        uint4 g1 = *(const uint4*)(cp + 8);
        __syncthreads();  // protect previous iteration's LDS reads
        const __half* bh0 = (const __half*)&b0;
        const __half* bh1 = (const __half*)&b1;
        const __half* gh0 = (const __half*)&g0;
        const __half* gh1 = (const __half*)&g1;
#pragma unroll
        for (int s = 0; s < 8; ++s) {
            bt[c0 + s][li] = __half2float(bh0[s]);
            bt[c0 + 8 + s][li] = __half2float(bh1[s]);
            ct[c0 + s][li] = __half2float(gh0[s]);
            ct[c0 + 8 + s][li] = __half2float(gh1[s]);
        }
        __syncthreads();
        const __half* ap = A + (size_t)(i0 + li) * NNODES + J + c0;
        uint4 a0 = *(const uint4*)ap;
        uint4 a1 = *(const uint4*)(ap + 8);
        const __half* ah0 = (const __half*)&a0;
        const __half* ah1 = (const __half*)&a1;
#pragma unroll
        for (int s = 0; s < 8; ++s) {
            float a = __half2float(ah0[s]);
            accO = fmaf(a, bt[li][c0 + s], accO);
            accE = fmaf(a, ct[li][c0 + s], accE);
        }
#pragma unroll
        for (int s = 0; s < 8; ++s) {
            float a = __half2float(ah1[s]);
            accO = fmaf(a, bt[li][c0 + 8 + s], accO);
            accE = fmaf(a, ct[li][c0 + 8 + s], accE);
        }
    }
    accO += __shfl_xor(accO, 1);
    accO += __shfl_xor(accO, 2);
    accE += __shfl_xor(accE, 1);
    accE += __shfl_xor(accE, 2);
    if (q == 0) {
        atomicAdd(&rw[(i0 + li) * LWALK + col_odd], accO);
        atomicAdd(&rw[(i0 + li) * LWALK + col_even], accE);
    }
}

// ---------- final linear ----------
__global__ void linear_k(const float* __restrict__ rw, const float* __restrict__ W,
                         const float* __restrict__ b, float* __restrict__ out) {
    int i = blockIdx.x * blockDim.x + threadIdx.x;
    if (i >= NNODES * ODIM) return;
    int s = i >> 3, d = i & 7;
    float acc = b[d];
#pragma unroll
    for (int k = 0; k < LWALK; ++k)
        acc = fmaf(rw[s * LWALK + k], W[d * LWALK + k], acc);
    out[i] = acc;
}

extern "C" void kernel_launch(void* const* d_in, const int* in_sizes, int n_in,
                              void* d_out, int out_size, void* d_ws, size_t ws_size,
                              hipStream_t stream) {
    const void* ei = d_in[0];
    int E = in_sizes[0] / 2;
    const float* W = (const float*)d_in[2];
    const float* bias = (const float*)d_in[3];
    float* out = (float*)d_out;

    char* ws = (char*)d_ws;
    size_t off = 0;
    auto alloc = [&](size_t bytes) -> char* {
        char* p = ws + off;
        off = (off + bytes + 255) & ~(size_t)255;
        return p;
    };
    int* flag = (int*)alloc(4);
    int* deg = (int*)alloc(NNODES * 4);
    int* cnt = (int*)alloc(NNODES * 4);
    int* rowptr = (int*)alloc((NNODES + 1) * 4);
    int* cursor = (int*)alloc(NNODES * 4);
    int* srcs = (int*)alloc((size_t)E * 4);
    float* vals = (float*)alloc((size_t)E * 4);
    float* rw = (float*)alloc(NNODES * LWALK * 4);
    __half* Xb = (__half*)alloc((size_t)NNODES * NNODES * 2);
    __half* Yb = (__half*)alloc((size_t)NNODES * NNODES * 2);

    hipMemsetAsync(deg, 0, NNODES * 4, stream);
    hipMemsetAsync(cnt, 0, NNODES * 4, stream);
    hipMemsetAsync(rw, 0, NNODES * LWALK * 4, stream);
    detect_fmt_k<<<1, 64, 0, stream>>>(ei, E, flag);
    build_deg_cnt_k<<<(E + 255) / 256, 256, 0, stream>>>(ei, E, deg, cnt, flag);
    scan_k<<<1, 1024, 0, stream>>>(cnt, rowptr, cursor);
    fill_csr_k<<<(E + 255) / 256, 256, 0, stream>>>(ei, E, deg, cursor, srcs, vals, flag);

    // X0 = I
    long long n16 = (long long)NNODES * NNODES / 8;  // uint4 units
    zeroh_k<<<(int)((n16 + 255) / 256), 256, 0, stream>>>((uint4*)Xb, n16);
    eyeh_k<<<(NNODES + 255) / 256, 256, 0, stream>>>(Xb);

    __half* X = Xb;
    __half* Y = Yb;
    for (int m = 1; m <= 8; ++m) {
        spmm_slab_k<<<NNODES * 8, 128, 0, stream>>>(X, Y, rowptr, srcs, vals);
        diag_h_k<<<(NNODES + 255) / 256, 256, 0, stream>>>(Y, rw, m - 1);
        if (m >= 5) {
            dim3 pg(NNODES / 64, 16);
            // odd walk 2m-1 (col 2m-2): sum_j X_m[i,j] * X_{m-1}[j,i]
            // even walk 2m (col 2m-1): sum_j X_m[i,j] * X_m[j,i]
            pairdiag2_k<<<pg, 256, 0, stream>>>(Y, X, rw, 2 * m - 2, 2 * m - 1);
        }
        __half* t = X; X = Y; Y = t;
    }
    linear_k<<<(NNODES * ODIM + 255) / 256, 256, 0, stream>>>(rw, W, bias, out);
}

// Round 5
// 425.846 us; speedup vs baseline: 5.8697x; 1.4635x over previous
//
#include <hip/hip_runtime.h>
#include <hip/hip_fp16.h>

#define NNODES 4096
#define LWALK 16
#define ODIM 8

typedef unsigned int uint4n __attribute__((ext_vector_type(4)));

// ---------- edge-index dtype detection (int32 vs int64 on device) ----------
__global__ void detect_fmt_k(const void* ei, int E, int* flag) {
    if (blockIdx.x == 0 && threadIdx.x == 0) {
        const long long* p = (const long long*)ei;
        int ok = 1;
        for (int i = 0; i < 64; ++i) {
            long long v = p[i];
            if (v < 0 || v >= NNODES) { ok = 0; break; }
        }
        *flag = ok;  // 1 => int64 layout, 0 => int32 layout
    }
}

__device__ __forceinline__ int load_idx(const void* p, int i, int fmt) {
    if (fmt) return (int)((const long long*)p)[i];
    return ((const int*)p)[i];
}

// ---------- degree + in-degree counts ----------
__global__ void build_deg_cnt_k(const void* ei, int E, int* deg, int* cnt,
                                const int* fmt) {
    int e = blockIdx.x * blockDim.x + threadIdx.x;
    if (e >= E) return;
    int f = *fmt;
    int r = load_idx(ei, e, f);
    int c = load_idx(ei, E + e, f);
    atomicAdd(&deg[r], 1);
    atomicAdd(&cnt[c], 1);
}

// ---------- exclusive scan over 4096 counts (single block, 1024 threads) ----------
__global__ void scan_k(const int* __restrict__ cnt, int* __restrict__ rowptr,
                       int* __restrict__ cursor) {
    __shared__ int sm[1024];
    int tid = threadIdx.x;
    int v0 = cnt[4 * tid + 0], v1 = cnt[4 * tid + 1];
    int v2 = cnt[4 * tid + 2], v3 = cnt[4 * tid + 3];
    int tsum = v0 + v1 + v2 + v3;
    sm[tid] = tsum;
    __syncthreads();
    int val = tsum;
    for (int off = 1; off < 1024; off <<= 1) {
        int t = (tid >= off) ? sm[tid - off] : 0;
        __syncthreads();
        val += t;
        sm[tid] = val;
        __syncthreads();
    }
    int excl = val - tsum;
    int p0 = excl, p1 = excl + v0, p2 = p1 + v1, p3 = p2 + v2;
    rowptr[4 * tid + 0] = p0; rowptr[4 * tid + 1] = p1;
    rowptr[4 * tid + 2] = p2; rowptr[4 * tid + 3] = p3;
    cursor[4 * tid + 0] = p0; cursor[4 * tid + 1] = p1;
    cursor[4 * tid + 2] = p2; cursor[4 * tid + 3] = p3;
    if (tid == 1023) rowptr[4096] = val;
}

// ---------- counting-sort fill of column-CSR ----------
__global__ void fill_csr_k(const void* ei, int E, const int* __restrict__ deg,
                           int* cursor, int* __restrict__ srcs,
                           float* __restrict__ vals, const int* fmt) {
    int e = blockIdx.x * blockDim.x + threadIdx.x;
    if (e >= E) return;
    int f = *fmt;
    int r = load_idx(ei, e, f);
    int c = load_idx(ei, E + e, f);
    int pos = atomicAdd(&cursor[c], 1);
    int d = deg[r];
    srcs[pos] = r;
    vals[pos] = 1.0f / (float)(d < 1 ? 1 : d);
}

// ---------- init X0 = I (fp16) ----------
__global__ void zeroh_k(uint4n* p, long long n) {
    long long i = (long long)blockIdx.x * blockDim.x + threadIdx.x;
    if (i < n) p[i] = (uint4n)(0u, 0u, 0u, 0u);
}

__global__ void eyeh_k(__half* X) {
    int i = blockIdx.x * blockDim.x + threadIdx.x;
    if (i < NNODES) X[(size_t)i * NNODES + i] = __float2half(1.0f);
}

// ---------- XCD-pinned wave-per-row-slab SpMM, diag fused ----------
// One wave handles (c, slab): 64 lanes x 16B = 1 KB = full 512-half slab row.
// Edge list staged 64-at-a-time into lane registers, broadcast via shfl,
// 4 independent gathers in flight.
__global__ __launch_bounds__(256) void spmm_wave_k(
    const __half* __restrict__ X, __half* __restrict__ Y,
    const int* __restrict__ rowptr, const int* __restrict__ srcs,
    const float* __restrict__ vals, float* __restrict__ rw, int kcol) {
    const int bid = blockIdx.x;          // 8192 blocks x 4 waves
    const int slab = bid & 7;            // XCD pin via round-robin dispatch
    const int wid = threadIdx.x >> 6;
    const int lane = threadIdx.x & 63;
    const int c = (bid >> 3) * 4 + wid;
    const int colo = slab * 512 + lane * 8;  // half offset within a row
    const __half* Xs = X + colo;

    const int beg = rowptr[c], end = rowptr[c + 1];
    float a[8];
#pragma unroll
    for (int u = 0; u < 8; ++u) a[u] = 0.f;

    for (int base = beg; base < end; base += 64) {
        int idx = base + lane;
        bool ok = idx < end;
        int rl = ok ? srcs[idx] : 0;
        float vl = ok ? vals[idx] : 0.f;
        int n = end - base;
        if (n > 64) n = 64;
        // padded groups of 4: OOB lanes carry v=0, r=0 (harmless row-0 gather)
        for (int j = 0; j < n; j += 4) {
            int r0 = __shfl(rl, j + 0); float v0 = __shfl(vl, j + 0);
            int r1 = __shfl(rl, j + 1); float v1 = __shfl(vl, j + 1);
            int r2 = __shfl(rl, j + 2); float v2 = __shfl(vl, j + 2);
            int r3 = __shfl(rl, j + 3); float v3 = __shfl(vl, j + 3);
            uint4n x0 = *(const uint4n*)(Xs + (size_t)r0 * NNODES);
            uint4n x1 = *(const uint4n*)(Xs + (size_t)r1 * NNODES);
            uint4n x2 = *(const uint4n*)(Xs + (size_t)r2 * NNODES);
            uint4n x3 = *(const uint4n*)(Xs + (size_t)r3 * NNODES);
            const __half* h0 = (const __half*)&x0;
            const __half* h1 = (const __half*)&x1;
            const __half* h2 = (const __half*)&x2;
            const __half* h3 = (const __half*)&x3;
#pragma unroll
            for (int u = 0; u < 8; ++u) {
                a[u] = fmaf(__half2float(h0[u]), v0, a[u]);
                a[u] = fmaf(__half2float(h1[u]), v1, a[u]);
                a[u] = fmaf(__half2float(h2[u]), v2, a[u]);
                a[u] = fmaf(__half2float(h3[u]), v3, a[u]);
            }
        }
    }

    // fused diagonal: Y[c,c] lives in slab c>>9, lane (c&511)>>3, elem c&7
    if ((c >> 9) == slab && lane == ((c & 511) >> 3)) {
        float d = 0.f;
#pragma unroll
        for (int u = 0; u < 8; ++u)
            if ((c & 7) == u) d = a[u];
        rw[c * LWALK + kcol] = d;
    }

    uint4n o;
    __half2* oh = (__half2*)&o;
#pragma unroll
    for (int u = 0; u < 4; ++u) oh[u] = __floats2half2_rn(a[2 * u], a[2 * u + 1]);
    // non-temporal: streaming Y-write must not evict the pinned X slab
    __builtin_nontemporal_store(o, (uint4n*)(Y + (size_t)c * NNODES + colo));
}

// ---------- fused paired diagonals (shares the A-row stream):
// rw[i,col_odd]  += sum_j A[i,j] * B[j,i]   (A=X_m, B=X_{m-1})
// rw[i,col_even] += sum_j A[i,j] * A[j,i]
__global__ __launch_bounds__(256) void pairdiag2_k(
    const __half* __restrict__ A, const __half* __restrict__ B,
    float* __restrict__ rw, int col_odd, int col_even) {
    __shared__ float bt[64][65];  // B^T tile
    __shared__ float ct[64][65];  // A^T tile
    const int i0 = blockIdx.x * 64;
    const int t = threadIdx.x;
    const int li = t >> 2;   // [0,64)
    const int q = t & 3;     // [0,4)
    const int c0 = q * 16;
    const int Jbeg = blockIdx.y * (NNODES / 16);
    const int Jend = Jbeg + (NNODES / 16);
    float accO = 0.f, accE = 0.f;
    for (int J = Jbeg; J < Jend; J += 64) {
        const __half* bp = B + (size_t)(J + li) * NNODES + i0 + c0;
        uint4n b0 = *(const uint4n*)bp;
        uint4n b1 = *(const uint4n*)(bp + 8);
        const __half* cp = A + (size_t)(J + li) * NNODES + i0 + c0;
        uint4n g0 = *(const uint4n*)cp;
        uint4n g1 = *(const uint4n*)(cp + 8);
        __syncthreads();  // protect previous iteration's LDS reads
        const __half* bh0 = (const __half*)&b0;
        const __half* bh1 = (const __half*)&b1;
        const __half* gh0 = (const __half*)&g0;
        const __half* gh1 = (const __half*)&g1;
#pragma unroll
        for (int s = 0; s < 8; ++s) {
            bt[c0 + s][li] = __half2float(bh0[s]);
            bt[c0 + 8 + s][li] = __half2float(bh1[s]);
            ct[c0 + s][li] = __half2float(gh0[s]);
            ct[c0 + 8 + s][li] = __half2float(gh1[s]);
        }
        __syncthreads();
        const __half* ap = A + (size_t)(i0 + li) * NNODES + J + c0;
        uint4n a0 = *(const uint4n*)ap;
        uint4n a1 = *(const uint4n*)(ap + 8);
        const __half* ah0 = (const __half*)&a0;
        const __half* ah1 = (const __half*)&a1;
#pragma unroll
        for (int s = 0; s < 8; ++s) {
            float a = __half2float(ah0[s]);
            accO = fmaf(a, bt[li][c0 + s], accO);
            accE = fmaf(a, ct[li][c0 + s], accE);
        }
#pragma unroll
        for (int s = 0; s < 8; ++s) {
            float a = __half2float(ah1[s]);
            accO = fmaf(a, bt[li][c0 + 8 + s], accO);
            accE = fmaf(a, ct[li][c0 + 8 + s], accE);
        }
    }
    accO += __shfl_xor(accO, 1);
    accO += __shfl_xor(accO, 2);
    accE += __shfl_xor(accE, 1);
    accE += __shfl_xor(accE, 2);
    if (q == 0) {
        atomicAdd(&rw[(i0 + li) * LWALK + col_odd], accO);
        atomicAdd(&rw[(i0 + li) * LWALK + col_even], accE);
    }
}

// ---------- final linear ----------
__global__ void linear_k(const float* __restrict__ rw, const float* __restrict__ W,
                         const float* __restrict__ b, float* __restrict__ out) {
    int i = blockIdx.x * blockDim.x + threadIdx.x;
    if (i >= NNODES * ODIM) return;
    int s = i >> 3, d = i & 7;
    float acc = b[d];
#pragma unroll
    for (int k = 0; k < LWALK; ++k)
        acc = fmaf(rw[s * LWALK + k], W[d * LWALK + k], acc);
    out[i] = acc;
}

extern "C" void kernel_launch(void* const* d_in, const int* in_sizes, int n_in,
                              void* d_out, int out_size, void* d_ws, size_t ws_size,
                              hipStream_t stream) {
    const void* ei = d_in[0];
    int E = in_sizes[0] / 2;
    const float* W = (const float*)d_in[2];
    const float* bias = (const float*)d_in[3];
    float* out = (float*)d_out;

    char* ws = (char*)d_ws;
    size_t off = 0;
    auto alloc = [&](size_t bytes) -> char* {
        char* p = ws + off;
        off = (off + bytes + 255) & ~(size_t)255;
        return p;
    };
    int* flag = (int*)alloc(4);
    int* deg = (int*)alloc(NNODES * 4);
    int* cnt = (int*)alloc(NNODES * 4);
    int* rowptr = (int*)alloc((NNODES + 1) * 4);
    int* cursor = (int*)alloc(NNODES * 4);
    int* srcs = (int*)alloc((size_t)E * 4);
    float* vals = (float*)alloc((size_t)E * 4);
    float* rw = (float*)alloc(NNODES * LWALK * 4);
    __half* Xb = (__half*)alloc((size_t)NNODES * NNODES * 2);
    __half* Yb = (__half*)alloc((size_t)NNODES * NNODES * 2);

    (void)hipMemsetAsync(deg, 0, NNODES * 4, stream);
    (void)hipMemsetAsync(cnt, 0, NNODES * 4, stream);
    (void)hipMemsetAsync(rw, 0, NNODES * LWALK * 4, stream);
    detect_fmt_k<<<1, 64, 0, stream>>>(ei, E, flag);
    build_deg_cnt_k<<<(E + 255) / 256, 256, 0, stream>>>(ei, E, deg, cnt, flag);
    scan_k<<<1, 1024, 0, stream>>>(cnt, rowptr, cursor);
    fill_csr_k<<<(E + 255) / 256, 256, 0, stream>>>(ei, E, deg, cursor, srcs, vals, flag);

    // X0 = I
    long long n16 = (long long)NNODES * NNODES / 8;  // 16B units
    zeroh_k<<<(int)((n16 + 255) / 256), 256, 0, stream>>>((uint4n*)Xb, n16);
    eyeh_k<<<(NNODES + 255) / 256, 256, 0, stream>>>(Xb);

    __half* X = Xb;
    __half* Y = Yb;
    for (int m = 1; m <= 8; ++m) {
        spmm_wave_k<<<NNODES * 8 / 4, 256, 0, stream>>>(X, Y, rowptr, srcs, vals,
                                                        rw, m - 1);
        if (m >= 5) {
            dim3 pg(NNODES / 64, 16);
            // odd walk 2m-1 (col 2m-2): sum_j X_m[i,j] * X_{m-1}[j,i]
            // even walk 2m (col 2m-1): sum_j X_m[i,j] * X_m[j,i]
            pairdiag2_k<<<pg, 256, 0, stream>>>(Y, X, rw, 2 * m - 2, 2 * m - 1);
        }
        __half* t = X; X = Y; Y = t;
    }
    linear_k<<<(NNODES * ODIM + 255) / 256, 256, 0, stream>>>(rw, W, bias, out);
}